// Round 23
// baseline (100.641 us; speedup 1.0000x reference)
//
#include <hip/hip_runtime.h>
#include <hip/hip_bf16.h>

#define T_TOK 2048
#define DMODEL 1024
#define HEXP 512
#define NEXP 16
#define TOPK 4
#define CAP 2048

typedef __attribute__((ext_vector_type(4))) float f32x4;
typedef __attribute__((ext_vector_type(8))) short short8;   // 8 bf16 (4 VGPRs) MFMA operand
typedef __attribute__((ext_vector_type(4))) unsigned short ush4;
typedef __attribute__((ext_vector_type(8))) unsigned short ush8;
typedef __attribute__((ext_vector_type(4))) int i32x4;
typedef __attribute__((ext_vector_type(4))) unsigned int u32x4;

static __device__ __forceinline__ unsigned short f2bf(float f) {
  union { float f; unsigned int u; } v; v.f = f;
  unsigned int r = v.u + 0x7FFFu + ((v.u >> 16) & 1u);
  return (unsigned short)(r >> 16);
}

// async global->LDS, 16B per lane; LDS dest is wave-uniform base + lane*16
static __device__ __forceinline__ void gl16(const unsigned short* g, unsigned short* l) {
  __builtin_amdgcn_global_load_lds(
      (const __attribute__((address_space(1))) unsigned int*)g,
      (__attribute__((address_space(3))) unsigned int*)l, 16, 0, 0);
}

// width-64 swizzled tile: phys ushort idx of logical (row, elem-col kb)
#define SWZ(r, kb) (((r) << 6) + ((((kb) >> 3) ^ ((r) & 7)) << 3))

#define WAITV4 asm volatile("s_waitcnt vmcnt(4)" ::: "memory")
#define WAITV0 asm volatile("s_waitcnt vmcnt(0)" ::: "memory")
#define BAR __builtin_amdgcn_s_barrier()

// ---------------- prep: router (blocks 0..511) || tcast (blocks 512..6655) ---------------
__global__ __launch_bounds__(256) void prep(const float* __restrict__ w_gate,
                                            const float* __restrict__ w_up,
                                            const float* __restrict__ w_down,
                                            unsigned short* __restrict__ wgT,
                                            unsigned short* __restrict__ wuT,
                                            unsigned short* __restrict__ wdT,
                                            const float* __restrict__ x,
                                            const float* __restrict__ cen,
                                            const float* __restrict__ bias,
                                            unsigned short* __restrict__ xbf,
                                            int* __restrict__ selIdx,
                                            float* __restrict__ selGate) {
  int blk = (int)blockIdx.x;
  if (blk >= 512) {
    __shared__ unsigned int ldsT[64][33];
    int idx = blk - 512;
    int sel = idx >> 11, bb = idx & 2047;
    const float* in; unsigned short* out; int R, C, rx, cy, e;
    if (sel == 0)      { in = w_gate; out = wgT; R = 1024; C = 512;
                         rx = bb & 15; cy = (bb >> 4) & 7; e = bb >> 7; }
    else if (sel == 1) { in = w_up;   out = wuT; R = 1024; C = 512;
                         rx = bb & 15; cy = (bb >> 4) & 7; e = bb >> 7; }
    else               { in = w_down; out = wdT; R = 512;  C = 1024;
                         rx = bb & 7;  cy = (bb >> 3) & 15; e = bb >> 7; }
    in  += (size_t)e * R * C;
    out += (size_t)e * R * C;
    int r0 = rx * 64, c0 = cy * 64;
    int tid = (int)threadIdx.x;
    int cc = (tid & 15) * 4;
    int pp = tid >> 4;
#pragma unroll
    for (int i = 0; i < 2; i++) {
      int p = pp + i * 16;
      int r = 2 * p;
      f32x4 va = *(const f32x4*)(in + (size_t)(r0 + r) * C + c0 + cc);
      f32x4 vb = *(const f32x4*)(in + (size_t)(r0 + r + 1) * C + c0 + cc);
#pragma unroll
      for (int k = 0; k < 4; k++) {
        unsigned int pk = (unsigned int)f2bf(va[k]) | ((unsigned int)f2bf(vb[k]) << 16);
        ldsT[cc + k][p] = pk;
      }
    }
    __syncthreads();
    int oc = tid >> 2;
    int sblk = (tid & 3) * 8;
    unsigned int q[8];
#pragma unroll
    for (int k = 0; k < 8; k++) q[k] = ldsT[oc][sblk + k];
    unsigned short* op = out + (size_t)(c0 + oc) * R + r0 + sblk * 2;
    *(u32x4*)(op)     = *(u32x4*)&q[0];
    *(u32x4*)(op + 8) = *(u32x4*)&q[4];
  } else {
    int tid = (int)threadIdx.x;
    int lane = tid & 63, wid = tid >> 6;
    int t = blk * 4 + wid;
    const float* xr = x + (size_t)t * DMODEL;
    f32x4 xv[4];
#pragma unroll
    for (int i = 0; i < 4; i++) xv[i] = *(const f32x4*)(xr + i * 256 + lane * 4);
    unsigned short* xb = xbf + (size_t)t * DMODEL;
#pragma unroll
    for (int i = 0; i < 4; i++) {
      ush4 b = { f2bf(xv[i][0]), f2bf(xv[i][1]), f2bf(xv[i][2]), f2bf(xv[i][3]) };
      *(ush4*)(xb + i * 256 + lane * 4) = b;
    }
    float p[16];
#pragma unroll
    for (int e = 0; e < NEXP; e++) p[e] = 0.f;
#pragma unroll
    for (int e = 0; e < NEXP; e++) {
      const float* ce = cen + (size_t)e * DMODEL;
#pragma unroll
      for (int i = 0; i < 4; i++) {
        f32x4 cv = *(const f32x4*)(ce + i * 256 + lane * 4);
#pragma unroll
        for (int j = 0; j < 4; j++) p[e] = fmaf(xv[i][j], cv[j], p[e]);
      }
    }
#pragma unroll
    for (int o = 32; o >= 1; o >>= 1) {
#pragma unroll
      for (int e = 0; e < NEXP; e++) p[e] += __shfl_xor(p[e], o);
    }
    float s[16];
#pragma unroll
    for (int e = 0; e < NEXP; e++) s[e] = 1.f / (1.f + expf(-(p[e] + bias[e])));
    int sel[4]; float val[4]; float gsum = 0.f;
#pragma unroll
    for (int k = 0; k < 4; k++) {
      float best = -1e30f; int bi = 0;
#pragma unroll
      for (int e = 0; e < NEXP; e++) {
        if (s[e] > best) { best = s[e]; bi = e; }
      }
      sel[k] = bi; val[k] = best; gsum += best;
#pragma unroll
      for (int e = 0; e < NEXP; e++) if (e == bi) s[e] = -1e30f;
    }
    float inv = 1.f / fmaxf(gsum, 1e-9f);
    if (lane == 0) {
      i32x4 si = { sel[0], sel[1], sel[2], sel[3] };
      f32x4 sg = { val[0] * inv, val[1] * inv, val[2] * inv, val[3] * inv };
      *(i32x4*)&selIdx[t * 4] = si;
      *(f32x4*)&selGate[t * 4] = sg;
    }
  }
}

// ---------------- buildlists: per-expert order-preserving compaction, no atomics ----------
__global__ __launch_bounds__(256) void buildlists(const int* __restrict__ selIdx,
                                                  const float* __restrict__ selGate,
                                                  int* __restrict__ cnt,
                                                  int* __restrict__ listTok,
                                                  float* __restrict__ listGate,
                                                  int* __restrict__ listSlot) {
  int e = blockIdx.x;
  int tid = (int)threadIdx.x, lane = tid & 63, w = tid >> 6;
  int i0 = tid * 32;
  int vals[32];
#pragma unroll
  for (int j = 0; j < 8; j++)
    *(i32x4*)&vals[j * 4] = *(const i32x4*)&selIdx[i0 + j * 4];
  int mycount = 0;
#pragma unroll
  for (int j = 0; j < 32; j++) mycount += (vals[j] == e) ? 1 : 0;
  int s = mycount;
#pragma unroll
  for (int o = 1; o < 64; o <<= 1) {
    int n = __shfl_up(s, o);
    if (lane >= o) s += n;
  }
  __shared__ int wtot[4];
  if (lane == 63) wtot[w] = s;
  __syncthreads();
  int wbase = 0;
#pragma unroll
  for (int j = 0; j < 4; j++) wbase += (j < w) ? wtot[j] : 0;
  int pos = wbase + s - mycount;
#pragma unroll
  for (int j = 0; j < 32; j++) {
    if (vals[j] == e) {
      int i = i0 + j;
      listTok[e * CAP + pos]  = i >> 2;
      listGate[e * CAP + pos] = selGate[i];
      listSlot[e * CAP + pos] = i;
      pos++;
    }
  }
  if (tid == 255) cnt[e] = pos;
}

// ---------------- FFN part 1: 128x64 tile, BK=64, dbuf + counted-vmcnt pipeline ----------
// 512 threads / 8 waves; per wave 4 gl16/step; tiles 2-deep in flight, vmcnt(4) certify.
__global__ __launch_bounds__(512) void ffn1(const unsigned short* __restrict__ xbf,
                                            const unsigned short* __restrict__ wgT,
                                            const unsigned short* __restrict__ wuT,
                                            const int* __restrict__ cnt,
                                            const int* __restrict__ listTok,
                                            const float* __restrict__ listGate,
                                            unsigned short* __restrict__ hbuf) {
  int b = (int)blockIdx.x;
  int xcd = b & 7, slot = b >> 3;
  int e = xcd + 8 * (slot >> 7);
  int tile = slot & 127;
  int my = tile >> 3;
  int nx = tile & 7;
  int c = cnt[e];
  int m0 = my * 128;
  if (m0 >= c) return;
  int n0 = nx * 64;
  __shared__ unsigned short sA[2][8192];   // 128 x 64 dbuf
  __shared__ unsigned short sG[2][4096];   // 64 x 64 dbuf
  __shared__ unsigned short sU[2][4096];
  __shared__ int sTok[128];
  __shared__ float sGate[128];
  int tid = (int)threadIdx.x;
  if (tid < 128) {
    int r = m0 + tid;
    sTok[tid]  = (r < c) ? listTok[e * CAP + r] : listTok[e * CAP];
    sGate[tid] = (r < c) ? listGate[e * CAP + r] : 0.f;
  }
  __syncthreads();
  int lane = tid & 63, wid = tid >> 6;          // wid 0..7
  int wr = wid >> 1, wc = wid & 1;              // wave out: rows wr*32.., cols wc*32..
  const unsigned short* wg = wgT + ((size_t)e * HEXP + n0) * DMODEL;
  const unsigned short* wu = wuT + ((size_t)e * HEXP + n0) * DMODEL;
  int rloc = lane >> 3;                  // 0..7
  int lg8 = lane & 7;
  // staging pointers (pre-swizzled global source), hoisted
  const unsigned short* pA[2];
#pragma unroll
  for (int i = 0; i < 2; i++) {
    int row = wid * 16 + i * 8 + rloc;
    int cg = lg8 ^ (row & 7);
    pA[i] = xbf + (size_t)sTok[row] * DMODEL + cg * 8;
  }
  int rG = wid * 8 + rloc;
  const unsigned short* pG = wg + (size_t)rG * DMODEL + (lg8 ^ (rG & 7)) * 8;
  const unsigned short* pU = wu + (size_t)rG * DMODEL + (lg8 ^ (rG & 7)) * 8;
  int rl = lane >> 4, lg = lane & 15;
  f32x4 ag[2][2] = {{{0,0,0,0},{0,0,0,0}},{{0,0,0,0},{0,0,0,0}}};
  f32x4 au[2][2] = {{{0,0,0,0},{0,0,0,0}},{{0,0,0,0},{0,0,0,0}}};

#define FFN1_STAGE(B, K0)                                         \
  do {                                                            \
    gl16(pA[0] + (K0), &sA[B][(wid * 16) * 64]);                  \
    gl16(pA[1] + (K0), &sA[B][(wid * 16 + 8) * 64]);              \
    gl16(pG + (K0), &sG[B][(wid * 8) * 64]);                      \
    gl16(pU + (K0), &sU[B][(wid * 8) * 64]);                      \
  } while (0)

#define FFN1_COMP(B)                                                              \
  do {                                                                            \
    _Pragma("unroll")                                                             \
    for (int kk = 0; kk < 2; kk++) {                                              \
      int kb = (kk << 5) + (rl << 3);                                             \
      short8 a[2], g[2], u[2];                                                    \
      _Pragma("unroll")                                                           \
      for (int m = 0; m < 2; m++)                                                 \
        a[m] = *(const short8*)&sA[B][SWZ((wr << 5) + lg + m * 16, kb)];          \
      _Pragma("unroll")                                                           \
      for (int n = 0; n < 2; n++) {                                               \
        g[n] = *(const short8*)&sG[B][SWZ((wc << 5) + lg + n * 16, kb)];          \
        u[n] = *(const short8*)&sU[B][SWZ((wc << 5) + lg + n * 16, kb)];          \
      }                                                                           \
      _Pragma("unroll")                                                           \
      for (int m = 0; m < 2; m++) {                                               \
        _Pragma("unroll")                                                         \
        for (int n = 0; n < 2; n++) {                                             \
          ag[m][n] = __builtin_amdgcn_mfma_f32_16x16x32_bf16(a[m], g[n], ag[m][n], 0, 0, 0); \
          au[m][n] = __builtin_amdgcn_mfma_f32_16x16x32_bf16(a[m], u[n], au[m][n], 0, 0, 0); \
        }                                                                         \
      }                                                                           \
    }                                                                             \
  } while (0)

  FFN1_STAGE(0, 0);
  FFN1_STAGE(1, 64);
#pragma unroll 1
  for (int t = 0; t < 16; t += 2) {
    // even step: buffer 0
    if (t < 15) WAITV4; else WAITV0;
    BAR;
    FFN1_COMP(0);
    BAR;
    if (t + 2 < 16) FFN1_STAGE(0, (t + 2) * 64);
    // odd step: buffer 1
    if (t + 1 < 15) WAITV4; else WAITV0;
    BAR;
    FFN1_COMP(1);
    BAR;
    if (t + 3 < 16) FFN1_STAGE(1, (t + 3) * 64);
  }

  int rlo = (lane >> 4) << 2;
  int cl = lane & 15;
#pragma unroll
  for (int m = 0; m < 2; m++) {
#pragma unroll
    for (int r = 0; r < 4; r++) {
      int row = (wr << 5) + m * 16 + rlo + r;
      int grow = m0 + row;
      if (grow < c) {
        float gwt = sGate[row];
#pragma unroll
        for (int n = 0; n < 2; n++) {
          int col = n0 + (wc << 5) + n * 16 + cl;
          float g = ag[m][n][r];
          float u = au[m][n][r];
          float sig = 1.f / (1.f + __expf(-g));
          float h = g * sig * u * gwt;
          hbuf[((size_t)e * CAP + grow) * HEXP + col] = f2bf(h);
        }
      }
    }
  }
}

// ---------------- FFN part 2: 128x128 tile, BK=64, dbuf + counted-vmcnt pipeline ---------
__global__ __launch_bounds__(512) void ffn2(const unsigned short* __restrict__ hbuf,
                                            const unsigned short* __restrict__ wdT,
                                            const int* __restrict__ cnt,
                                            const int* __restrict__ listSlot,
                                            float* __restrict__ y) {
  int b = (int)blockIdx.x;
  int xcd = b & 7, slot = b >> 3;
  int e = xcd + 8 * (slot >> 7);
  int tile = slot & 127;
  int my = tile >> 3;
  int nx = tile & 7;
  int c = cnt[e];
  int m0 = my * 128;
  if (m0 >= c) return;
  int n0 = nx * 128;
  __shared__ unsigned short sA[2][8192];   // 128 x 64 dbuf
  __shared__ unsigned short sB[2][8192];   // 128 x 64 dbuf
  __shared__ int sSlot[128];
  int tid = (int)threadIdx.x;
  if (tid < 128) {
    int r = m0 + tid;
    sSlot[tid] = (r < c) ? listSlot[e * CAP + r] : 0;
  }
  __syncthreads();
  int lane = tid & 63, wid = tid >> 6;
  int wr = wid >> 1, wc = wid & 1;      // wave out: rows wr*32.., cols wc*64..
  const unsigned short* ha = hbuf + ((size_t)e * CAP + m0) * HEXP;
  const unsigned short* wd = wdT + ((size_t)e * DMODEL + n0) * HEXP;
  int rloc = lane >> 3, lg8 = lane & 7;
  const unsigned short* pA[2];
  const unsigned short* pB[2];
#pragma unroll
  for (int i = 0; i < 2; i++) {
    int row = wid * 16 + i * 8 + rloc;
    int cg = lg8 ^ (row & 7);
    pA[i] = ha + (size_t)row * HEXP + cg * 8;
    pB[i] = wd + (size_t)row * HEXP + cg * 8;
  }
  int rl = lane >> 4, lg = lane & 15;
  f32x4 acc[2][4];
#pragma unroll
  for (int m = 0; m < 2; m++)
#pragma unroll
    for (int n = 0; n < 4; n++) acc[m][n] = f32x4{0, 0, 0, 0};

#define FFN2_STAGE(B, K0)                                   \
  do {                                                      \
    gl16(pA[0] + (K0), &sA[B][(wid * 16) * 64]);            \
    gl16(pA[1] + (K0), &sA[B][(wid * 16 + 8) * 64]);        \
    gl16(pB[0] + (K0), &sB[B][(wid * 16) * 64]);            \
    gl16(pB[1] + (K0), &sB[B][(wid * 16 + 8) * 64]);        \
  } while (0)

#define FFN2_COMP(B)                                                              \
  do {                                                                            \
    _Pragma("unroll")                                                             \
    for (int kk = 0; kk < 2; kk++) {                                              \
      int kb = (kk << 5) + (rl << 3);                                             \
      short8 a[2], bb[4];                                                         \
      _Pragma("unroll")                                                           \
      for (int m = 0; m < 2; m++)                                                 \
        a[m] = *(const short8*)&sA[B][SWZ((wr << 5) + lg + m * 16, kb)];          \
      _Pragma("unroll")                                                           \
      for (int n = 0; n < 4; n++)                                                 \
        bb[n] = *(const short8*)&sB[B][SWZ((wc << 6) + lg + n * 16, kb)];         \
      _Pragma("unroll")                                                           \
      for (int m = 0; m < 2; m++) {                                               \
        _Pragma("unroll")                                                         \
        for (int n = 0; n < 4; n++)                                               \
          acc[m][n] = __builtin_amdgcn_mfma_f32_16x16x32_bf16(a[m], bb[n], acc[m][n], 0, 0, 0); \
      }                                                                           \
    }                                                                             \
  } while (0)

  FFN2_STAGE(0, 0);
  FFN2_STAGE(1, 64);
#pragma unroll 1
  for (int t = 0; t < 8; t += 2) {
    if (t < 7) WAITV4; else WAITV0;
    BAR;
    FFN2_COMP(0);
    BAR;
    if (t + 2 < 8) FFN2_STAGE(0, (t + 2) * 64);
    if (t + 1 < 7) WAITV4; else WAITV0;
    BAR;
    FFN2_COMP(1);
    BAR;
    if (t + 3 < 8) FFN2_STAGE(1, (t + 3) * 64);
  }

  int rlo = (lane >> 4) << 2;
  int cl = lane & 15;
#pragma unroll
  for (int m = 0; m < 2; m++) {
#pragma unroll
    for (int r = 0; r < 4; r++) {
      int row = (wr << 5) + m * 16 + rlo + r;
      int grow = m0 + row;
      if (grow < c) {
        int slot2 = sSlot[row];
#pragma unroll
        for (int n = 0; n < 4; n++) {
          int col = n0 + (wc << 6) + n * 16 + cl;
          y[(size_t)slot2 * DMODEL + col] = acc[m][n][r];
        }
      }
    }
  }
}

// ---------------- final reduce over the 4 expert slots + scale ---------------------------
__global__ __launch_bounds__(256) void reducek(const float* __restrict__ y,
                                               const float* __restrict__ scale,
                                               float* __restrict__ out) {
  int i = blockIdx.x * 256 + (int)threadIdx.x;
  int t = i >> 8;
  int d = (i & 255) << 2;
  const float* yb = y + (size_t)t * 4 * DMODEL + d;
  f32x4 s = *(const f32x4*)(yb);
  s += *(const f32x4*)(yb + DMODEL);
  s += *(const f32x4*)(yb + 2 * DMODEL);
  s += *(const f32x4*)(yb + 3 * DMODEL);
  float sc = scale[0];
  s *= sc;
  *(f32x4*)(out + (size_t)t * DMODEL + d) = s;
}

extern "C" void kernel_launch(void* const* d_in, const int* in_sizes, int n_in,
                              void* d_out, int out_size, void* d_ws, size_t ws_size,
                              hipStream_t stream) {
  const float* x      = (const float*)d_in[0];
  const float* cen    = (const float*)d_in[1];
  const float* bias   = (const float*)d_in[2];
  const float* w_gate = (const float*)d_in[3];
  const float* w_up   = (const float*)d_in[4];
  const float* w_down = (const float*)d_in[5];
  const float* scale  = (const float*)d_in[6];
  float* out = (float*)d_out;

  char* ws = (char*)d_ws;
  unsigned short* xbf  = (unsigned short*)(ws);                 //  4 MB
  unsigned short* wgT  = (unsigned short*)(ws + 4194304);       // 16 MB  [E][H][D] bf16
  unsigned short* wuT  = (unsigned short*)(ws + 20971520);      // 16 MB
  unsigned short* wdT  = (unsigned short*)(ws + 37748736);      // 16 MB  [E][D][H] bf16
  unsigned short* hbuf = (unsigned short*)(ws + 54525952);      // 32 MB  [E][CAP][H] bf16
  float*          y    = (float*)(ws + 88080384);               // 32 MB  [T*4][D] f32
  int*            cnt  = (int*)(ws + 121634816);
  int*        listTok  = (int*)(ws + 121635072);
  float*     listGate  = (float*)(ws + 121766144);
  int*       listSlot  = (int*)(ws + 121897216);
  int*         selIdx  = (int*)(ws + 122028288);                // 32 KB
  float*      selGate  = (float*)(ws + 122061056);              // 32 KB

  prep<<<dim3(6656), 256, 0, stream>>>(w_gate, w_up, w_down, wgT, wuT, wdT,
                                       x, cen, bias, xbf, selIdx, selGate);
  buildlists<<<dim3(16), 256, 0, stream>>>(selIdx, selGate, cnt, listTok, listGate, listSlot);
  ffn1<<<dim3(2048), 512, 0, stream>>>(xbf, wgT, wuT, cnt, listTok, listGate, hbuf);
  ffn2<<<dim3(2048), 512, 0, stream>>>(hbuf, wdT, cnt, listSlot, y);
  reducek<<<dim3(2048), 256, 0, stream>>>(y, scale, out);
}

// Round 25
// 98.574 us; speedup vs baseline: 1.0210x; 1.0210x over previous
//
#include <hip/hip_runtime.h>
#include <hip/hip_bf16.h>

#define T_TOK 2048
#define DMODEL 1024
#define HEXP 512
#define NEXP 16
#define TOPK 4
#define CAP 2048

typedef __attribute__((ext_vector_type(4))) float f32x4;
typedef __attribute__((ext_vector_type(8))) short short8;   // 8 bf16 (4 VGPRs) MFMA operand
typedef __attribute__((ext_vector_type(4))) unsigned short ush4;
typedef __attribute__((ext_vector_type(8))) unsigned short ush8;
typedef __attribute__((ext_vector_type(4))) int i32x4;
typedef __attribute__((ext_vector_type(4))) unsigned int u32x4;

static __device__ __forceinline__ unsigned short f2bf(float f) {
  union { float f; unsigned int u; } v; v.f = f;
  unsigned int r = v.u + 0x7FFFu + ((v.u >> 16) & 1u);
  return (unsigned short)(r >> 16);
}

// async global->LDS, 16B per lane; LDS dest is wave-uniform base + lane*16
static __device__ __forceinline__ void gl16(const unsigned short* g, unsigned short* l) {
  __builtin_amdgcn_global_load_lds(
      (const __attribute__((address_space(1))) unsigned int*)g,
      (__attribute__((address_space(3))) unsigned int*)l, 16, 0, 0);
}

// width-128 swizzled tile: phys ushort idx of logical (row, elem-col kb)
#define SWZ128(r, kb) (((r) << 7) + ((((kb) >> 3) ^ ((r) & 15)) << 3))

// ---------------- prep: router (blocks 0..511) || tcast (blocks 512..6655) ---------------
__global__ __launch_bounds__(256) void prep(const float* __restrict__ w_gate,
                                            const float* __restrict__ w_up,
                                            const float* __restrict__ w_down,
                                            unsigned short* __restrict__ wgT,
                                            unsigned short* __restrict__ wuT,
                                            unsigned short* __restrict__ wdT,
                                            const float* __restrict__ x,
                                            const float* __restrict__ cen,
                                            const float* __restrict__ bias,
                                            unsigned short* __restrict__ xbf,
                                            int* __restrict__ selIdx,
                                            float* __restrict__ selGate) {
  int blk = (int)blockIdx.x;
  if (blk >= 512) {
    __shared__ unsigned int ldsT[64][33];
    int idx = blk - 512;
    int sel = idx >> 11, bb = idx & 2047;
    const float* in; unsigned short* out; int R, C, rx, cy, e;
    if (sel == 0)      { in = w_gate; out = wgT; R = 1024; C = 512;
                         rx = bb & 15; cy = (bb >> 4) & 7; e = bb >> 7; }
    else if (sel == 1) { in = w_up;   out = wuT; R = 1024; C = 512;
                         rx = bb & 15; cy = (bb >> 4) & 7; e = bb >> 7; }
    else               { in = w_down; out = wdT; R = 512;  C = 1024;
                         rx = bb & 7;  cy = (bb >> 3) & 15; e = bb >> 7; }
    in  += (size_t)e * R * C;
    out += (size_t)e * R * C;
    int r0 = rx * 64, c0 = cy * 64;
    int tid = (int)threadIdx.x;
    int cc = (tid & 15) * 4;
    int pp = tid >> 4;
#pragma unroll
    for (int i = 0; i < 2; i++) {
      int p = pp + i * 16;
      int r = 2 * p;
      f32x4 va = *(const f32x4*)(in + (size_t)(r0 + r) * C + c0 + cc);
      f32x4 vb = *(const f32x4*)(in + (size_t)(r0 + r + 1) * C + c0 + cc);
#pragma unroll
      for (int k = 0; k < 4; k++) {
        unsigned int pk = (unsigned int)f2bf(va[k]) | ((unsigned int)f2bf(vb[k]) << 16);
        ldsT[cc + k][p] = pk;
      }
    }
    __syncthreads();
    int oc = tid >> 2;
    int sblk = (tid & 3) * 8;
    unsigned int q[8];
#pragma unroll
    for (int k = 0; k < 8; k++) q[k] = ldsT[oc][sblk + k];
    unsigned short* op = out + (size_t)(c0 + oc) * R + r0 + sblk * 2;
    *(u32x4*)(op)     = *(u32x4*)&q[0];
    *(u32x4*)(op + 8) = *(u32x4*)&q[4];
  } else {
    int tid = (int)threadIdx.x;
    int lane = tid & 63, wid = tid >> 6;
    int t = blk * 4 + wid;
    const float* xr = x + (size_t)t * DMODEL;
    f32x4 xv[4];
#pragma unroll
    for (int i = 0; i < 4; i++) xv[i] = *(const f32x4*)(xr + i * 256 + lane * 4);
    unsigned short* xb = xbf + (size_t)t * DMODEL;
#pragma unroll
    for (int i = 0; i < 4; i++) {
      ush4 b = { f2bf(xv[i][0]), f2bf(xv[i][1]), f2bf(xv[i][2]), f2bf(xv[i][3]) };
      *(ush4*)(xb + i * 256 + lane * 4) = b;
    }
    float p[16];
#pragma unroll
    for (int e = 0; e < NEXP; e++) p[e] = 0.f;
#pragma unroll
    for (int e = 0; e < NEXP; e++) {
      const float* ce = cen + (size_t)e * DMODEL;
#pragma unroll
      for (int i = 0; i < 4; i++) {
        f32x4 cv = *(const f32x4*)(ce + i * 256 + lane * 4);
#pragma unroll
        for (int j = 0; j < 4; j++) p[e] = fmaf(xv[i][j], cv[j], p[e]);
      }
    }
#pragma unroll
    for (int o = 32; o >= 1; o >>= 1) {
#pragma unroll
      for (int e = 0; e < NEXP; e++) p[e] += __shfl_xor(p[e], o);
    }
    float s[16];
#pragma unroll
    for (int e = 0; e < NEXP; e++) s[e] = 1.f / (1.f + expf(-(p[e] + bias[e])));
    int sel[4]; float val[4]; float gsum = 0.f;
#pragma unroll
    for (int k = 0; k < 4; k++) {
      float best = -1e30f; int bi = 0;
#pragma unroll
      for (int e = 0; e < NEXP; e++) {
        if (s[e] > best) { best = s[e]; bi = e; }
      }
      sel[k] = bi; val[k] = best; gsum += best;
#pragma unroll
      for (int e = 0; e < NEXP; e++) if (e == bi) s[e] = -1e30f;
    }
    float inv = 1.f / fmaxf(gsum, 1e-9f);
    if (lane == 0) {
      i32x4 si = { sel[0], sel[1], sel[2], sel[3] };
      f32x4 sg = { val[0] * inv, val[1] * inv, val[2] * inv, val[3] * inv };
      *(i32x4*)&selIdx[t * 4] = si;
      *(f32x4*)&selGate[t * 4] = sg;
    }
  }
}

// ---------------- buildlists: per-expert order-preserving compaction, no atomics ----------
__global__ __launch_bounds__(256) void buildlists(const int* __restrict__ selIdx,
                                                  const float* __restrict__ selGate,
                                                  int* __restrict__ cnt,
                                                  int* __restrict__ listTok,
                                                  float* __restrict__ listGate,
                                                  int* __restrict__ listSlot) {
  int e = blockIdx.x;
  int tid = (int)threadIdx.x, lane = tid & 63, w = tid >> 6;
  int i0 = tid * 32;
  int vals[32];
#pragma unroll
  for (int j = 0; j < 8; j++)
    *(i32x4*)&vals[j * 4] = *(const i32x4*)&selIdx[i0 + j * 4];
  int mycount = 0;
#pragma unroll
  for (int j = 0; j < 32; j++) mycount += (vals[j] == e) ? 1 : 0;
  int s = mycount;
#pragma unroll
  for (int o = 1; o < 64; o <<= 1) {
    int n = __shfl_up(s, o);
    if (lane >= o) s += n;
  }
  __shared__ int wtot[4];
  if (lane == 63) wtot[w] = s;
  __syncthreads();
  int wbase = 0;
#pragma unroll
  for (int j = 0; j < 4; j++) wbase += (j < w) ? wtot[j] : 0;
  int pos = wbase + s - mycount;
#pragma unroll
  for (int j = 0; j < 32; j++) {
    if (vals[j] == e) {
      int i = i0 + j;
      listTok[e * CAP + pos]  = i >> 2;
      listGate[e * CAP + pos] = selGate[i];
      listSlot[e * CAP + pos] = i;
      pos++;
    }
  }
  if (tid == 255) cnt[e] = pos;
}

// ---------------- FFN part 1: 128x64 tile, BK=128, 8 waves, XCD affinity -----------------
// 512 threads; wave (wr 0..3, wc 0..1) owns 32x32 out; staging 8 gl16/wave.
__global__ __launch_bounds__(512) void ffn1(const unsigned short* __restrict__ xbf,
                                            const unsigned short* __restrict__ wgT,
                                            const unsigned short* __restrict__ wuT,
                                            const int* __restrict__ cnt,
                                            const int* __restrict__ listTok,
                                            const float* __restrict__ listGate,
                                            unsigned short* __restrict__ hbuf) {
  int b = (int)blockIdx.x;
  int xcd = b & 7, slot = b >> 3;
  int e = xcd + 8 * (slot >> 7);
  int tile = slot & 127;
  int my = tile >> 3;                   // 0..15 m-tile
  int nx = tile & 7;                    // 0..7 n-tile
  int c = cnt[e];
  int m0 = my * 128;
  if (m0 >= c) return;
  int n0 = nx * 64;
  __shared__ unsigned short sA[16384];   // 128 x 128 swizzled
  __shared__ unsigned short sG[8192];    // 64 x 128
  __shared__ unsigned short sU[8192];    // 64 x 128
  __shared__ int sTok[128];
  __shared__ float sGate[128];
  int tid = (int)threadIdx.x;
  if (tid < 128) {
    int r = m0 + tid;
    sTok[tid]  = (r < c) ? listTok[e * CAP + r] : listTok[e * CAP];
    sGate[tid] = (r < c) ? listGate[e * CAP + r] : 0.f;
  }
  __syncthreads();
  int lane = tid & 63, wid = tid >> 6;          // wid 0..7
  int wr = wid >> 1, wc = wid & 1;              // wave out: rows wr*32.., cols wc*32..
  const unsigned short* wg = wgT + ((size_t)e * HEXP + n0) * DMODEL;
  const unsigned short* wu = wuT + ((size_t)e * HEXP + n0) * DMODEL;
  int rl = lane >> 4;                    // 0..3
  int lg = lane & 15;                    // granule slot
  const unsigned short* pA[4];
#pragma unroll
  for (int i = 0; i < 4; i++) {
    int lr = wid * 16 + i * 4 + rl;
    int cg = lg ^ (lr & 15);
    pA[i] = xbf + (size_t)sTok[lr] * DMODEL + cg * 8;
  }
  const unsigned short* pG[2];
  const unsigned short* pU[2];
#pragma unroll
  for (int j = 0; j < 2; j++) {
    int lr = wid * 8 + j * 4 + rl;
    int cg = lg ^ (lr & 15);
    pG[j] = wg + (size_t)lr * DMODEL + cg * 8;
    pU[j] = wu + (size_t)lr * DMODEL + cg * 8;
  }
  f32x4 ag[2][2] = {{{0,0,0,0},{0,0,0,0}},{{0,0,0,0},{0,0,0,0}}};
  f32x4 au[2][2] = {{{0,0,0,0},{0,0,0,0}},{{0,0,0,0},{0,0,0,0}}};
#pragma unroll 1
  for (int k0 = 0; k0 < DMODEL; k0 += 128) {
    __syncthreads();
#pragma unroll
    for (int i = 0; i < 4; i++)
      gl16(pA[i] + k0, sA + (wid * 16 + i * 4) * 128);
#pragma unroll
    for (int j = 0; j < 2; j++) {
      gl16(pG[j] + k0, sG + (wid * 8 + j * 4) * 128);
      gl16(pU[j] + k0, sU + (wid * 8 + j * 4) * 128);
    }
    __syncthreads();
#pragma unroll
    for (int kk = 0; kk < 4; kk++) {
      int kb = (kk << 5) + (rl << 3);
      short8 a[2], g[2], u[2];
#pragma unroll
      for (int m = 0; m < 2; m++)
        a[m] = *(const short8*)&sA[SWZ128((wr << 5) + lg + m * 16, kb)];
#pragma unroll
      for (int n = 0; n < 2; n++) {
        g[n] = *(const short8*)&sG[SWZ128((wc << 5) + lg + n * 16, kb)];
        u[n] = *(const short8*)&sU[SWZ128((wc << 5) + lg + n * 16, kb)];
      }
#pragma unroll
      for (int m = 0; m < 2; m++) {
#pragma unroll
        for (int n = 0; n < 2; n++) {
          ag[m][n] = __builtin_amdgcn_mfma_f32_16x16x32_bf16(a[m], g[n], ag[m][n], 0, 0, 0);
          au[m][n] = __builtin_amdgcn_mfma_f32_16x16x32_bf16(a[m], u[n], au[m][n], 0, 0, 0);
        }
      }
    }
  }
  int rlo = (lane >> 4) << 2;
  int cl = lane & 15;
#pragma unroll
  for (int m = 0; m < 2; m++) {
#pragma unroll
    for (int r = 0; r < 4; r++) {
      int row = (wr << 5) + m * 16 + rlo + r;
      int grow = m0 + row;
      if (grow < c) {
        float gwt = sGate[row];
#pragma unroll
        for (int n = 0; n < 2; n++) {
          int col = n0 + (wc << 5) + n * 16 + cl;
          float g = ag[m][n][r];
          float u = au[m][n][r];
          float sig = 1.f / (1.f + __expf(-g));
          float h = g * sig * u * gwt;
          hbuf[((size_t)e * CAP + grow) * HEXP + col] = f2bf(h);
        }
      }
    }
  }
}

// ---------------- FFN part 2: 128x128 tile, BK=128, 8 waves, XCD affinity ----------------
// 512 threads; wave (wr 0..3, wc 0..1) owns 32x64 out.
__global__ __launch_bounds__(512) void ffn2(const unsigned short* __restrict__ hbuf,
                                            const unsigned short* __restrict__ wdT,
                                            const int* __restrict__ cnt,
                                            const int* __restrict__ listSlot,
                                            float* __restrict__ y) {
  int b = (int)blockIdx.x;
  int xcd = b & 7, slot = b >> 3;
  int e = xcd + 8 * (slot >> 7);
  int tile = slot & 127;
  int my = tile >> 3;                   // 0..15 m-tile
  int nx = tile & 7;                    // 0..7 n-tile (128 wide)
  int c = cnt[e];
  int m0 = my * 128;
  if (m0 >= c) return;
  int n0 = nx * 128;
  __shared__ unsigned short sA[16384];   // 128 x 128
  __shared__ unsigned short sB[16384];   // 128 x 128
  __shared__ int sSlot[128];
  int tid = (int)threadIdx.x;
  if (tid < 128) {
    int r = m0 + tid;
    sSlot[tid] = (r < c) ? listSlot[e * CAP + r] : 0;
  }
  __syncthreads();
  int lane = tid & 63, wid = tid >> 6;
  int wr = wid >> 1, wc = wid & 1;      // wave out: rows wr*32.., cols wc*64..
  const unsigned short* ha = hbuf + ((size_t)e * CAP + m0) * HEXP;
  const unsigned short* wd = wdT + ((size_t)e * DMODEL + n0) * HEXP;
  int rl = lane >> 4;
  int lg = lane & 15;
  const unsigned short* pA[4];
  const unsigned short* pB[4];
#pragma unroll
  for (int i = 0; i < 4; i++) {
    int lr = wid * 16 + i * 4 + rl;
    int cg = lg ^ (lr & 15);
    pA[i] = ha + (size_t)lr * HEXP + cg * 8;
    pB[i] = wd + (size_t)lr * HEXP + cg * 8;
  }
  f32x4 acc[2][4];
#pragma unroll
  for (int m = 0; m < 2; m++)
#pragma unroll
    for (int n = 0; n < 4; n++) acc[m][n] = f32x4{0, 0, 0, 0};
#pragma unroll 1
  for (int k0 = 0; k0 < HEXP; k0 += 128) {
    __syncthreads();
#pragma unroll
    for (int i = 0; i < 4; i++) {
      gl16(pA[i] + k0, sA + (wid * 16 + i * 4) * 128);
      gl16(pB[i] + k0, sB + (wid * 16 + i * 4) * 128);
    }
    __syncthreads();
#pragma unroll
    for (int kk = 0; kk < 4; kk++) {
      int kb = (kk << 5) + (rl << 3);
      short8 a[2], bb[4];
#pragma unroll
      for (int m = 0; m < 2; m++)
        a[m] = *(const short8*)&sA[SWZ128((wr << 5) + lg + m * 16, kb)];
#pragma unroll
      for (int n = 0; n < 4; n++)
        bb[n] = *(const short8*)&sB[SWZ128((wc << 6) + lg + n * 16, kb)];
#pragma unroll
      for (int m = 0; m < 2; m++) {
#pragma unroll
        for (int n = 0; n < 4; n++)
          acc[m][n] = __builtin_amdgcn_mfma_f32_16x16x32_bf16(a[m], bb[n], acc[m][n], 0, 0, 0);
      }
    }
  }
  int rlo = (lane >> 4) << 2;
  int cl = lane & 15;
#pragma unroll
  for (int m = 0; m < 2; m++) {
#pragma unroll
    for (int r = 0; r < 4; r++) {
      int row = (wr << 5) + m * 16 + rlo + r;
      int grow = m0 + row;
      if (grow < c) {
        int slot2 = sSlot[row];
#pragma unroll
        for (int n = 0; n < 4; n++) {
          int col = n0 + (wc << 6) + n * 16 + cl;
          y[(size_t)slot2 * DMODEL + col] = acc[m][n][r];
        }
      }
    }
  }
}

// ---------------- final reduce over the 4 expert slots + scale ---------------------------
__global__ __launch_bounds__(256) void reducek(const float* __restrict__ y,
                                               const float* __restrict__ scale,
                                               float* __restrict__ out) {
  int i = blockIdx.x * 256 + (int)threadIdx.x;
  int t = i >> 8;
  int d = (i & 255) << 2;
  const float* yb = y + (size_t)t * 4 * DMODEL + d;
  f32x4 s = *(const f32x4*)(yb);
  s += *(const f32x4*)(yb + DMODEL);
  s += *(const f32x4*)(yb + 2 * DMODEL);
  s += *(const f32x4*)(yb + 3 * DMODEL);
  float sc = scale[0];
  s *= sc;
  *(f32x4*)(out + (size_t)t * DMODEL + d) = s;
}

extern "C" void kernel_launch(void* const* d_in, const int* in_sizes, int n_in,
                              void* d_out, int out_size, void* d_ws, size_t ws_size,
                              hipStream_t stream) {
  const float* x      = (const float*)d_in[0];
  const float* cen    = (const float*)d_in[1];
  const float* bias   = (const float*)d_in[2];
  const float* w_gate = (const float*)d_in[3];
  const float* w_up   = (const float*)d_in[4];
  const float* w_down = (const float*)d_in[5];
  const float* scale  = (const float*)d_in[6];
  float* out = (float*)d_out;

  char* ws = (char*)d_ws;
  unsigned short* xbf  = (unsigned short*)(ws);                 //  4 MB
  unsigned short* wgT  = (unsigned short*)(ws + 4194304);       // 16 MB  [E][H][D] bf16
  unsigned short* wuT  = (unsigned short*)(ws + 20971520);      // 16 MB
  unsigned short* wdT  = (unsigned short*)(ws + 37748736);      // 16 MB  [E][D][H] bf16
  unsigned short* hbuf = (unsigned short*)(ws + 54525952);      // 32 MB  [E][CAP][H] bf16
  float*          y    = (float*)(ws + 88080384);               // 32 MB  [T*4][D] f32
  int*            cnt  = (int*)(ws + 121634816);
  int*        listTok  = (int*)(ws + 121635072);
  float*     listGate  = (float*)(ws + 121766144);
  int*       listSlot  = (int*)(ws + 121897216);
  int*         selIdx  = (int*)(ws + 122028288);                // 32 KB
  float*      selGate  = (float*)(ws + 122061056);              // 32 KB

  prep<<<dim3(6656), 256, 0, stream>>>(w_gate, w_up, w_down, wgT, wuT, wdT,
                                       x, cen, bias, xbf, selIdx, selGate);
  buildlists<<<dim3(16), 256, 0, stream>>>(selIdx, selGate, cnt, listTok, listGate, listSlot);
  ffn1<<<dim3(2048), 512, 0, stream>>>(xbf, wgT, wuT, cnt, listTok, listGate, hbuf);
  ffn2<<<dim3(2048), 512, 0, stream>>>(hbuf, wdT, cnt, listSlot, y);
  reducek<<<dim3(2048), 256, 0, stream>>>(y, scale, out);
}

// Round 26
// 96.253 us; speedup vs baseline: 1.0456x; 1.0241x over previous
//
#include <hip/hip_runtime.h>
#include <hip/hip_bf16.h>

#define T_TOK 2048
#define DMODEL 1024
#define HEXP 512
#define NEXP 16
#define TOPK 4
#define CAP 2048

typedef __attribute__((ext_vector_type(4))) float f32x4;
typedef __attribute__((ext_vector_type(8))) short short8;   // 8 bf16 (4 VGPRs) MFMA operand
typedef __attribute__((ext_vector_type(4))) unsigned short ush4;
typedef __attribute__((ext_vector_type(8))) unsigned short ush8;
typedef __attribute__((ext_vector_type(4))) int i32x4;
typedef __attribute__((ext_vector_type(4))) unsigned int u32x4;

static __device__ __forceinline__ unsigned short f2bf(float f) {
  union { float f; unsigned int u; } v; v.f = f;
  unsigned int r = v.u + 0x7FFFu + ((v.u >> 16) & 1u);
  return (unsigned short)(r >> 16);
}

// async global->LDS, 16B per lane; LDS dest is wave-uniform base + lane*16
static __device__ __forceinline__ void gl16(const unsigned short* g, unsigned short* l) {
  __builtin_amdgcn_global_load_lds(
      (const __attribute__((address_space(1))) unsigned int*)g,
      (__attribute__((address_space(3))) unsigned int*)l, 16, 0, 0);
}

// width-128 swizzled tile: phys ushort idx of logical (row, elem-col kb)
#define SWZ128(r, kb) (((r) << 7) + ((((kb) >> 3) ^ ((r) & 15)) << 3))

// ---------------- prep: router (blocks 0..511) || tcast (blocks 512..6655) ---------------
__global__ __launch_bounds__(256) void prep(const float* __restrict__ w_gate,
                                            const float* __restrict__ w_up,
                                            const float* __restrict__ w_down,
                                            unsigned short* __restrict__ wgT,
                                            unsigned short* __restrict__ wuT,
                                            unsigned short* __restrict__ wdT,
                                            const float* __restrict__ x,
                                            const float* __restrict__ cen,
                                            const float* __restrict__ bias,
                                            unsigned short* __restrict__ xbf,
                                            int* __restrict__ selIdx,
                                            float* __restrict__ selGate) {
  int blk = (int)blockIdx.x;
  if (blk >= 512) {
    __shared__ unsigned int ldsT[64][33];
    int idx = blk - 512;
    int sel = idx >> 11, bb = idx & 2047;
    const float* in; unsigned short* out; int R, C, rx, cy, e;
    if (sel == 0)      { in = w_gate; out = wgT; R = 1024; C = 512;
                         rx = bb & 15; cy = (bb >> 4) & 7; e = bb >> 7; }
    else if (sel == 1) { in = w_up;   out = wuT; R = 1024; C = 512;
                         rx = bb & 15; cy = (bb >> 4) & 7; e = bb >> 7; }
    else               { in = w_down; out = wdT; R = 512;  C = 1024;
                         rx = bb & 7;  cy = (bb >> 3) & 15; e = bb >> 7; }
    in  += (size_t)e * R * C;
    out += (size_t)e * R * C;
    int r0 = rx * 64, c0 = cy * 64;
    int tid = (int)threadIdx.x;
    int cc = (tid & 15) * 4;
    int pp = tid >> 4;
#pragma unroll
    for (int i = 0; i < 2; i++) {
      int p = pp + i * 16;
      int r = 2 * p;
      f32x4 va = *(const f32x4*)(in + (size_t)(r0 + r) * C + c0 + cc);
      f32x4 vb = *(const f32x4*)(in + (size_t)(r0 + r + 1) * C + c0 + cc);
#pragma unroll
      for (int k = 0; k < 4; k++) {
        unsigned int pk = (unsigned int)f2bf(va[k]) | ((unsigned int)f2bf(vb[k]) << 16);
        ldsT[cc + k][p] = pk;
      }
    }
    __syncthreads();
    int oc = tid >> 2;
    int sblk = (tid & 3) * 8;
    unsigned int q[8];
#pragma unroll
    for (int k = 0; k < 8; k++) q[k] = ldsT[oc][sblk + k];
    unsigned short* op = out + (size_t)(c0 + oc) * R + r0 + sblk * 2;
    *(u32x4*)(op)     = *(u32x4*)&q[0];
    *(u32x4*)(op + 8) = *(u32x4*)&q[4];
  } else {
    int tid = (int)threadIdx.x;
    int lane = tid & 63, wid = tid >> 6;
    int t = blk * 4 + wid;
    const float* xr = x + (size_t)t * DMODEL;
    f32x4 xv[4];
#pragma unroll
    for (int i = 0; i < 4; i++) xv[i] = *(const f32x4*)(xr + i * 256 + lane * 4);
    unsigned short* xb = xbf + (size_t)t * DMODEL;
#pragma unroll
    for (int i = 0; i < 4; i++) {
      ush4 b = { f2bf(xv[i][0]), f2bf(xv[i][1]), f2bf(xv[i][2]), f2bf(xv[i][3]) };
      *(ush4*)(xb + i * 256 + lane * 4) = b;
    }
    float p[16];
#pragma unroll
    for (int e = 0; e < NEXP; e++) p[e] = 0.f;
#pragma unroll
    for (int e = 0; e < NEXP; e++) {
      const float* ce = cen + (size_t)e * DMODEL;
#pragma unroll
      for (int i = 0; i < 4; i++) {
        f32x4 cv = *(const f32x4*)(ce + i * 256 + lane * 4);
#pragma unroll
        for (int j = 0; j < 4; j++) p[e] = fmaf(xv[i][j], cv[j], p[e]);
      }
    }
#pragma unroll
    for (int o = 32; o >= 1; o >>= 1) {
#pragma unroll
      for (int e = 0; e < NEXP; e++) p[e] += __shfl_xor(p[e], o);
    }
    float s[16];
#pragma unroll
    for (int e = 0; e < NEXP; e++) s[e] = 1.f / (1.f + expf(-(p[e] + bias[e])));
    int sel[4]; float val[4]; float gsum = 0.f;
#pragma unroll
    for (int k = 0; k < 4; k++) {
      float best = -1e30f; int bi = 0;
#pragma unroll
      for (int e = 0; e < NEXP; e++) {
        if (s[e] > best) { best = s[e]; bi = e; }
      }
      sel[k] = bi; val[k] = best; gsum += best;
#pragma unroll
      for (int e = 0; e < NEXP; e++) if (e == bi) s[e] = -1e30f;
    }
    float inv = 1.f / fmaxf(gsum, 1e-9f);
    if (lane == 0) {
      i32x4 si = { sel[0], sel[1], sel[2], sel[3] };
      f32x4 sg = { val[0] * inv, val[1] * inv, val[2] * inv, val[3] * inv };
      *(i32x4*)&selIdx[t * 4] = si;
      *(f32x4*)&selGate[t * 4] = sg;
    }
  }
}

// ---------------- buildlists: per-expert order-preserving compaction, no atomics ----------
__global__ __launch_bounds__(256) void buildlists(const int* __restrict__ selIdx,
                                                  const float* __restrict__ selGate,
                                                  int* __restrict__ cnt,
                                                  int* __restrict__ listTok,
                                                  float* __restrict__ listGate,
                                                  int* __restrict__ listSlot) {
  int e = blockIdx.x;
  int tid = (int)threadIdx.x, lane = tid & 63, w = tid >> 6;
  int i0 = tid * 32;
  int vals[32];
#pragma unroll
  for (int j = 0; j < 8; j++)
    *(i32x4*)&vals[j * 4] = *(const i32x4*)&selIdx[i0 + j * 4];
  int mycount = 0;
#pragma unroll
  for (int j = 0; j < 32; j++) mycount += (vals[j] == e) ? 1 : 0;
  int s = mycount;
#pragma unroll
  for (int o = 1; o < 64; o <<= 1) {
    int n = __shfl_up(s, o);
    if (lane >= o) s += n;
  }
  __shared__ int wtot[4];
  if (lane == 63) wtot[w] = s;
  __syncthreads();
  int wbase = 0;
#pragma unroll
  for (int j = 0; j < 4; j++) wbase += (j < w) ? wtot[j] : 0;
  int pos = wbase + s - mycount;
#pragma unroll
  for (int j = 0; j < 32; j++) {
    if (vals[j] == e) {
      int i = i0 + j;
      listTok[e * CAP + pos]  = i >> 2;
      listGate[e * CAP + pos] = selGate[i];
      listSlot[e * CAP + pos] = i;
      pos++;
    }
  }
  if (tid == 255) cnt[e] = pos;
}

// ---------------- FFN part 1: 64x64 tile, BK=128, 8 waves, XCD affinity ------------------
// grid 4096; wave (wr 0..3, wc 0..1) owns 16x32 out; small acc -> higher occupancy probe.
__global__ __launch_bounds__(512) void ffn1(const unsigned short* __restrict__ xbf,
                                            const unsigned short* __restrict__ wgT,
                                            const unsigned short* __restrict__ wuT,
                                            const int* __restrict__ cnt,
                                            const int* __restrict__ listTok,
                                            const float* __restrict__ listGate,
                                            unsigned short* __restrict__ hbuf) {
  int b = (int)blockIdx.x;
  int xcd = b & 7, slot = b >> 3;
  int e = xcd + 8 * (slot >> 8);        // 256 tiles/expert
  int tile = slot & 255;
  int my = tile >> 3;                   // 0..31 m-tile (64 rows each)
  int nx = tile & 7;                    // 0..7 n-tile
  int c = cnt[e];
  int m0 = my * 64;
  if (m0 >= c) return;
  int n0 = nx * 64;
  __shared__ unsigned short sA[8192];    // 64 x 128 swizzled
  __shared__ unsigned short sG[8192];    // 64 x 128
  __shared__ unsigned short sU[8192];    // 64 x 128
  __shared__ int sTok[64];
  __shared__ float sGate[64];
  int tid = (int)threadIdx.x;
  if (tid < 64) {
    int r = m0 + tid;
    sTok[tid]  = (r < c) ? listTok[e * CAP + r] : listTok[e * CAP];
    sGate[tid] = (r < c) ? listGate[e * CAP + r] : 0.f;
  }
  __syncthreads();
  int lane = tid & 63, wid = tid >> 6;          // wid 0..7
  int wr = wid >> 1, wc = wid & 1;              // wave out: rows wr*16.., cols wc*32..
  const unsigned short* wg = wgT + ((size_t)e * HEXP + n0) * DMODEL;
  const unsigned short* wu = wuT + ((size_t)e * HEXP + n0) * DMODEL;
  int rl = lane >> 4;                    // 0..3
  int lg = lane & 15;                    // granule slot
  // staging: each wave covers rows [wid*8, wid*8+8) of each 64-row tile, 2 issues of 4 rows
  const unsigned short* pA[2];
  const unsigned short* pG[2];
  const unsigned short* pU[2];
#pragma unroll
  for (int i = 0; i < 2; i++) {
    int lr = wid * 8 + i * 4 + rl;
    int cg = lg ^ (lr & 15);
    pA[i] = xbf + (size_t)sTok[lr] * DMODEL + cg * 8;
    pG[i] = wg + (size_t)lr * DMODEL + cg * 8;
    pU[i] = wu + (size_t)lr * DMODEL + cg * 8;
  }
  f32x4 ag[2] = {{0,0,0,0},{0,0,0,0}};
  f32x4 au[2] = {{0,0,0,0},{0,0,0,0}};
#pragma unroll 1
  for (int k0 = 0; k0 < DMODEL; k0 += 128) {
    __syncthreads();
#pragma unroll
    for (int i = 0; i < 2; i++) {
      gl16(pA[i] + k0, sA + (wid * 8 + i * 4) * 128);
      gl16(pG[i] + k0, sG + (wid * 8 + i * 4) * 128);
      gl16(pU[i] + k0, sU + (wid * 8 + i * 4) * 128);
    }
    __syncthreads();
#pragma unroll
    for (int kk = 0; kk < 4; kk++) {
      int kb = (kk << 5) + (rl << 3);
      short8 a, g[2], u[2];
      a = *(const short8*)&sA[SWZ128((wr << 4) + lg, kb)];
#pragma unroll
      for (int n = 0; n < 2; n++) {
        g[n] = *(const short8*)&sG[SWZ128((wc << 5) + lg + n * 16, kb)];
        u[n] = *(const short8*)&sU[SWZ128((wc << 5) + lg + n * 16, kb)];
      }
#pragma unroll
      for (int n = 0; n < 2; n++) {
        ag[n] = __builtin_amdgcn_mfma_f32_16x16x32_bf16(a, g[n], ag[n], 0, 0, 0);
        au[n] = __builtin_amdgcn_mfma_f32_16x16x32_bf16(a, u[n], au[n], 0, 0, 0);
      }
    }
  }
  int rlo = (lane >> 4) << 2;
  int cl = lane & 15;
#pragma unroll
  for (int r = 0; r < 4; r++) {
    int row = (wr << 4) + rlo + r;
    int grow = m0 + row;
    if (grow < c) {
      float gwt = sGate[row];
#pragma unroll
      for (int n = 0; n < 2; n++) {
        int col = n0 + (wc << 5) + n * 16 + cl;
        float g = ag[n][r];
        float u = au[n][r];
        float sig = 1.f / (1.f + __expf(-g));
        float h = g * sig * u * gwt;
        hbuf[((size_t)e * CAP + grow) * HEXP + col] = f2bf(h);
      }
    }
  }
}

// ---------------- FFN part 2: 128x128 tile, BK=128, 8 waves, XCD affinity ----------------
// 512 threads; wave (wr 0..3, wc 0..1) owns 32x64 out.
__global__ __launch_bounds__(512) void ffn2(const unsigned short* __restrict__ hbuf,
                                            const unsigned short* __restrict__ wdT,
                                            const int* __restrict__ cnt,
                                            const int* __restrict__ listSlot,
                                            float* __restrict__ y) {
  int b = (int)blockIdx.x;
  int xcd = b & 7, slot = b >> 3;
  int e = xcd + 8 * (slot >> 7);
  int tile = slot & 127;
  int my = tile >> 3;                   // 0..15 m-tile
  int nx = tile & 7;                    // 0..7 n-tile (128 wide)
  int c = cnt[e];
  int m0 = my * 128;
  if (m0 >= c) return;
  int n0 = nx * 128;
  __shared__ unsigned short sA[16384];   // 128 x 128
  __shared__ unsigned short sB[16384];   // 128 x 128
  __shared__ int sSlot[128];
  int tid = (int)threadIdx.x;
  if (tid < 128) {
    int r = m0 + tid;
    sSlot[tid] = (r < c) ? listSlot[e * CAP + r] : 0;
  }
  __syncthreads();
  int lane = tid & 63, wid = tid >> 6;
  int wr = wid >> 1, wc = wid & 1;      // wave out: rows wr*32.., cols wc*64..
  const unsigned short* ha = hbuf + ((size_t)e * CAP + m0) * HEXP;
  const unsigned short* wd = wdT + ((size_t)e * DMODEL + n0) * HEXP;
  int rl = lane >> 4;
  int lg = lane & 15;
  const unsigned short* pA[4];
  const unsigned short* pB[4];
#pragma unroll
  for (int i = 0; i < 4; i++) {
    int lr = wid * 16 + i * 4 + rl;
    int cg = lg ^ (lr & 15);
    pA[i] = ha + (size_t)lr * HEXP + cg * 8;
    pB[i] = wd + (size_t)lr * HEXP + cg * 8;
  }
  f32x4 acc[2][4];
#pragma unroll
  for (int m = 0; m < 2; m++)
#pragma unroll
    for (int n = 0; n < 4; n++) acc[m][n] = f32x4{0, 0, 0, 0};
#pragma unroll 1
  for (int k0 = 0; k0 < HEXP; k0 += 128) {
    __syncthreads();
#pragma unroll
    for (int i = 0; i < 4; i++) {
      gl16(pA[i] + k0, sA + (wid * 16 + i * 4) * 128);
      gl16(pB[i] + k0, sB + (wid * 16 + i * 4) * 128);
    }
    __syncthreads();
#pragma unroll
    for (int kk = 0; kk < 4; kk++) {
      int kb = (kk << 5) + (rl << 3);
      short8 a[2], bb[4];
#pragma unroll
      for (int m = 0; m < 2; m++)
        a[m] = *(const short8*)&sA[SWZ128((wr << 5) + lg + m * 16, kb)];
#pragma unroll
      for (int n = 0; n < 4; n++)
        bb[n] = *(const short8*)&sB[SWZ128((wc << 6) + lg + n * 16, kb)];
#pragma unroll
      for (int m = 0; m < 2; m++) {
#pragma unroll
        for (int n = 0; n < 4; n++)
          acc[m][n] = __builtin_amdgcn_mfma_f32_16x16x32_bf16(a[m], bb[n], acc[m][n], 0, 0, 0);
      }
    }
  }
  int rlo = (lane >> 4) << 2;
  int cl = lane & 15;
#pragma unroll
  for (int m = 0; m < 2; m++) {
#pragma unroll
    for (int r = 0; r < 4; r++) {
      int row = (wr << 5) + m * 16 + rlo + r;
      int grow = m0 + row;
      if (grow < c) {
        int slot2 = sSlot[row];
#pragma unroll
        for (int n = 0; n < 4; n++) {
          int col = n0 + (wc << 6) + n * 16 + cl;
          y[(size_t)slot2 * DMODEL + col] = acc[m][n][r];
        }
      }
    }
  }
}

// ---------------- final reduce over the 4 expert slots + scale ---------------------------
__global__ __launch_bounds__(256) void reducek(const float* __restrict__ y,
                                               const float* __restrict__ scale,
                                               float* __restrict__ out) {
  int i = blockIdx.x * 256 + (int)threadIdx.x;
  int t = i >> 8;
  int d = (i & 255) << 2;
  const float* yb = y + (size_t)t * 4 * DMODEL + d;
  f32x4 s = *(const f32x4*)(yb);
  s += *(const f32x4*)(yb + DMODEL);
  s += *(const f32x4*)(yb + 2 * DMODEL);
  s += *(const f32x4*)(yb + 3 * DMODEL);
  float sc = scale[0];
  s *= sc;
  *(f32x4*)(out + (size_t)t * DMODEL + d) = s;
}

extern "C" void kernel_launch(void* const* d_in, const int* in_sizes, int n_in,
                              void* d_out, int out_size, void* d_ws, size_t ws_size,
                              hipStream_t stream) {
  const float* x      = (const float*)d_in[0];
  const float* cen    = (const float*)d_in[1];
  const float* bias   = (const float*)d_in[2];
  const float* w_gate = (const float*)d_in[3];
  const float* w_up   = (const float*)d_in[4];
  const float* w_down = (const float*)d_in[5];
  const float* scale  = (const float*)d_in[6];
  float* out = (float*)d_out;

  char* ws = (char*)d_ws;
  unsigned short* xbf  = (unsigned short*)(ws);                 //  4 MB
  unsigned short* wgT  = (unsigned short*)(ws + 4194304);       // 16 MB  [E][H][D] bf16
  unsigned short* wuT  = (unsigned short*)(ws + 20971520);      // 16 MB
  unsigned short* wdT  = (unsigned short*)(ws + 37748736);      // 16 MB  [E][D][H] bf16
  unsigned short* hbuf = (unsigned short*)(ws + 54525952);      // 32 MB  [E][CAP][H] bf16
  float*          y    = (float*)(ws + 88080384);               // 32 MB  [T*4][D] f32
  int*            cnt  = (int*)(ws + 121634816);
  int*        listTok  = (int*)(ws + 121635072);
  float*     listGate  = (float*)(ws + 121766144);
  int*       listSlot  = (int*)(ws + 121897216);
  int*         selIdx  = (int*)(ws + 122028288);                // 32 KB
  float*      selGate  = (float*)(ws + 122061056);              // 32 KB

  prep<<<dim3(6656), 256, 0, stream>>>(w_gate, w_up, w_down, wgT, wuT, wdT,
                                       x, cen, bias, xbf, selIdx, selGate);
  buildlists<<<dim3(16), 256, 0, stream>>>(selIdx, selGate, cnt, listTok, listGate, listSlot);
  ffn1<<<dim3(4096), 512, 0, stream>>>(xbf, wgT, wuT, cnt, listTok, listGate, hbuf);
  ffn2<<<dim3(2048), 512, 0, stream>>>(hbuf, wdT, cnt, listSlot, y);
  reducek<<<dim3(2048), 256, 0, stream>>>(y, scale, out);
}

// Round 27
// 93.626 us; speedup vs baseline: 1.0749x; 1.0281x over previous
//
#include <hip/hip_runtime.h>
#include <hip/hip_bf16.h>

#define T_TOK 2048
#define DMODEL 1024
#define HEXP 512
#define NEXP 16
#define TOPK 4
#define CAP 2048

typedef __attribute__((ext_vector_type(4))) float f32x4;
typedef __attribute__((ext_vector_type(8))) short short8;   // 8 bf16 (4 VGPRs) MFMA operand
typedef __attribute__((ext_vector_type(4))) unsigned short ush4;
typedef __attribute__((ext_vector_type(8))) unsigned short ush8;
typedef __attribute__((ext_vector_type(4))) int i32x4;
typedef __attribute__((ext_vector_type(4))) unsigned int u32x4;

static __device__ __forceinline__ unsigned short f2bf(float f) {
  union { float f; unsigned int u; } v; v.f = f;
  unsigned int r = v.u + 0x7FFFu + ((v.u >> 16) & 1u);
  return (unsigned short)(r >> 16);
}

// async global->LDS, 16B per lane; LDS dest is wave-uniform base + lane*16
static __device__ __forceinline__ void gl16(const unsigned short* g, unsigned short* l) {
  __builtin_amdgcn_global_load_lds(
      (const __attribute__((address_space(1))) unsigned int*)g,
      (__attribute__((address_space(3))) unsigned int*)l, 16, 0, 0);
}

// width-128 swizzled tile: phys ushort idx of logical (row, elem-col kb)
#define SWZ128(r, kb) (((r) << 7) + ((((kb) >> 3) ^ ((r) & 15)) << 3))

// ---------------- prep: router (blocks 0..511) || tcast (blocks 512..6655) ---------------
__global__ __launch_bounds__(256) void prep(const float* __restrict__ w_gate,
                                            const float* __restrict__ w_up,
                                            const float* __restrict__ w_down,
                                            unsigned short* __restrict__ wgT,
                                            unsigned short* __restrict__ wuT,
                                            unsigned short* __restrict__ wdT,
                                            const float* __restrict__ x,
                                            const float* __restrict__ cen,
                                            const float* __restrict__ bias,
                                            unsigned short* __restrict__ xbf,
                                            int* __restrict__ selIdx,
                                            float* __restrict__ selGate) {
  int blk = (int)blockIdx.x;
  if (blk >= 512) {
    __shared__ unsigned int ldsT[64][33];
    int idx = blk - 512;
    int sel = idx >> 11, bb = idx & 2047;
    const float* in; unsigned short* out; int R, C, rx, cy, e;
    if (sel == 0)      { in = w_gate; out = wgT; R = 1024; C = 512;
                         rx = bb & 15; cy = (bb >> 4) & 7; e = bb >> 7; }
    else if (sel == 1) { in = w_up;   out = wuT; R = 1024; C = 512;
                         rx = bb & 15; cy = (bb >> 4) & 7; e = bb >> 7; }
    else               { in = w_down; out = wdT; R = 512;  C = 1024;
                         rx = bb & 7;  cy = (bb >> 3) & 15; e = bb >> 7; }
    in  += (size_t)e * R * C;
    out += (size_t)e * R * C;
    int r0 = rx * 64, c0 = cy * 64;
    int tid = (int)threadIdx.x;
    int cc = (tid & 15) * 4;
    int pp = tid >> 4;
#pragma unroll
    for (int i = 0; i < 2; i++) {
      int p = pp + i * 16;
      int r = 2 * p;
      f32x4 va = *(const f32x4*)(in + (size_t)(r0 + r) * C + c0 + cc);
      f32x4 vb = *(const f32x4*)(in + (size_t)(r0 + r + 1) * C + c0 + cc);
#pragma unroll
      for (int k = 0; k < 4; k++) {
        unsigned int pk = (unsigned int)f2bf(va[k]) | ((unsigned int)f2bf(vb[k]) << 16);
        ldsT[cc + k][p] = pk;
      }
    }
    __syncthreads();
    int oc = tid >> 2;
    int sblk = (tid & 3) * 8;
    unsigned int q[8];
#pragma unroll
    for (int k = 0; k < 8; k++) q[k] = ldsT[oc][sblk + k];
    unsigned short* op = out + (size_t)(c0 + oc) * R + r0 + sblk * 2;
    *(u32x4*)(op)     = *(u32x4*)&q[0];
    *(u32x4*)(op + 8) = *(u32x4*)&q[4];
  } else {
    int tid = (int)threadIdx.x;
    int lane = tid & 63, wid = tid >> 6;
    int t = blk * 4 + wid;
    const float* xr = x + (size_t)t * DMODEL;
    f32x4 xv[4];
#pragma unroll
    for (int i = 0; i < 4; i++) xv[i] = *(const f32x4*)(xr + i * 256 + lane * 4);
    unsigned short* xb = xbf + (size_t)t * DMODEL;
#pragma unroll
    for (int i = 0; i < 4; i++) {
      ush4 b = { f2bf(xv[i][0]), f2bf(xv[i][1]), f2bf(xv[i][2]), f2bf(xv[i][3]) };
      *(ush4*)(xb + i * 256 + lane * 4) = b;
    }
    float p[16];
#pragma unroll
    for (int e = 0; e < NEXP; e++) p[e] = 0.f;
#pragma unroll
    for (int e = 0; e < NEXP; e++) {
      const float* ce = cen + (size_t)e * DMODEL;
#pragma unroll
      for (int i = 0; i < 4; i++) {
        f32x4 cv = *(const f32x4*)(ce + i * 256 + lane * 4);
#pragma unroll
        for (int j = 0; j < 4; j++) p[e] = fmaf(xv[i][j], cv[j], p[e]);
      }
    }
#pragma unroll
    for (int o = 32; o >= 1; o >>= 1) {
#pragma unroll
      for (int e = 0; e < NEXP; e++) p[e] += __shfl_xor(p[e], o);
    }
    float s[16];
#pragma unroll
    for (int e = 0; e < NEXP; e++) s[e] = 1.f / (1.f + expf(-(p[e] + bias[e])));
    int sel[4]; float val[4]; float gsum = 0.f;
#pragma unroll
    for (int k = 0; k < 4; k++) {
      float best = -1e30f; int bi = 0;
#pragma unroll
      for (int e = 0; e < NEXP; e++) {
        if (s[e] > best) { best = s[e]; bi = e; }
      }
      sel[k] = bi; val[k] = best; gsum += best;
#pragma unroll
      for (int e = 0; e < NEXP; e++) if (e == bi) s[e] = -1e30f;
    }
    float inv = 1.f / fmaxf(gsum, 1e-9f);
    if (lane == 0) {
      i32x4 si = { sel[0], sel[1], sel[2], sel[3] };
      f32x4 sg = { val[0] * inv, val[1] * inv, val[2] * inv, val[3] * inv };
      *(i32x4*)&selIdx[t * 4] = si;
      *(f32x4*)&selGate[t * 4] = sg;
    }
  }
}

// ---------------- buildlists: per-expert order-preserving compaction, no atomics ----------
__global__ __launch_bounds__(256) void buildlists(const int* __restrict__ selIdx,
                                                  const float* __restrict__ selGate,
                                                  int* __restrict__ cnt,
                                                  int* __restrict__ listTok,
                                                  float* __restrict__ listGate,
                                                  int* __restrict__ listSlot) {
  int e = blockIdx.x;
  int tid = (int)threadIdx.x, lane = tid & 63, w = tid >> 6;
  int i0 = tid * 32;
  int vals[32];
#pragma unroll
  for (int j = 0; j < 8; j++)
    *(i32x4*)&vals[j * 4] = *(const i32x4*)&selIdx[i0 + j * 4];
  int mycount = 0;
#pragma unroll
  for (int j = 0; j < 32; j++) mycount += (vals[j] == e) ? 1 : 0;
  int s = mycount;
#pragma unroll
  for (int o = 1; o < 64; o <<= 1) {
    int n = __shfl_up(s, o);
    if (lane >= o) s += n;
  }
  __shared__ int wtot[4];
  if (lane == 63) wtot[w] = s;
  __syncthreads();
  int wbase = 0;
#pragma unroll
  for (int j = 0; j < 4; j++) wbase += (j < w) ? wtot[j] : 0;
  int pos = wbase + s - mycount;
#pragma unroll
  for (int j = 0; j < 32; j++) {
    if (vals[j] == e) {
      int i = i0 + j;
      listTok[e * CAP + pos]  = i >> 2;
      listGate[e * CAP + pos] = selGate[i];
      listSlot[e * CAP + pos] = i;
      pos++;
    }
  }
  if (tid == 255) cnt[e] = pos;
}

// ---------------- FFN part 1: 64x64 tile, BK=128, 8 waves, XCD affinity ------------------
// grid 4096; wave (wr 0..3, wc 0..1) owns 16x32 out; small acc -> high occupancy.
__global__ __launch_bounds__(512) void ffn1(const unsigned short* __restrict__ xbf,
                                            const unsigned short* __restrict__ wgT,
                                            const unsigned short* __restrict__ wuT,
                                            const int* __restrict__ cnt,
                                            const int* __restrict__ listTok,
                                            const float* __restrict__ listGate,
                                            unsigned short* __restrict__ hbuf) {
  int b = (int)blockIdx.x;
  int xcd = b & 7, slot = b >> 3;
  int e = xcd + 8 * (slot >> 8);        // 256 tiles/expert
  int tile = slot & 255;
  int my = tile >> 3;                   // 0..31 m-tile (64 rows each)
  int nx = tile & 7;                    // 0..7 n-tile
  int c = cnt[e];
  int m0 = my * 64;
  if (m0 >= c) return;
  int n0 = nx * 64;
  __shared__ unsigned short sA[8192];    // 64 x 128 swizzled
  __shared__ unsigned short sG[8192];    // 64 x 128
  __shared__ unsigned short sU[8192];    // 64 x 128
  __shared__ int sTok[64];
  __shared__ float sGate[64];
  int tid = (int)threadIdx.x;
  if (tid < 64) {
    int r = m0 + tid;
    sTok[tid]  = (r < c) ? listTok[e * CAP + r] : listTok[e * CAP];
    sGate[tid] = (r < c) ? listGate[e * CAP + r] : 0.f;
  }
  __syncthreads();
  int lane = tid & 63, wid = tid >> 6;          // wid 0..7
  int wr = wid >> 1, wc = wid & 1;              // wave out: rows wr*16.., cols wc*32..
  const unsigned short* wg = wgT + ((size_t)e * HEXP + n0) * DMODEL;
  const unsigned short* wu = wuT + ((size_t)e * HEXP + n0) * DMODEL;
  int rl = lane >> 4;                    // 0..3
  int lg = lane & 15;                    // granule slot
  const unsigned short* pA[2];
  const unsigned short* pG[2];
  const unsigned short* pU[2];
#pragma unroll
  for (int i = 0; i < 2; i++) {
    int lr = wid * 8 + i * 4 + rl;
    int cg = lg ^ (lr & 15);
    pA[i] = xbf + (size_t)sTok[lr] * DMODEL + cg * 8;
    pG[i] = wg + (size_t)lr * DMODEL + cg * 8;
    pU[i] = wu + (size_t)lr * DMODEL + cg * 8;
  }
  f32x4 ag[2] = {{0,0,0,0},{0,0,0,0}};
  f32x4 au[2] = {{0,0,0,0},{0,0,0,0}};
#pragma unroll 1
  for (int k0 = 0; k0 < DMODEL; k0 += 128) {
    __syncthreads();
#pragma unroll
    for (int i = 0; i < 2; i++) {
      gl16(pA[i] + k0, sA + (wid * 8 + i * 4) * 128);
      gl16(pG[i] + k0, sG + (wid * 8 + i * 4) * 128);
      gl16(pU[i] + k0, sU + (wid * 8 + i * 4) * 128);
    }
    __syncthreads();
#pragma unroll
    for (int kk = 0; kk < 4; kk++) {
      int kb = (kk << 5) + (rl << 3);
      short8 a, g[2], u[2];
      a = *(const short8*)&sA[SWZ128((wr << 4) + lg, kb)];
#pragma unroll
      for (int n = 0; n < 2; n++) {
        g[n] = *(const short8*)&sG[SWZ128((wc << 5) + lg + n * 16, kb)];
        u[n] = *(const short8*)&sU[SWZ128((wc << 5) + lg + n * 16, kb)];
      }
#pragma unroll
      for (int n = 0; n < 2; n++) {
        ag[n] = __builtin_amdgcn_mfma_f32_16x16x32_bf16(a, g[n], ag[n], 0, 0, 0);
        au[n] = __builtin_amdgcn_mfma_f32_16x16x32_bf16(a, u[n], au[n], 0, 0, 0);
      }
    }
  }
  int rlo = (lane >> 4) << 2;
  int cl = lane & 15;
#pragma unroll
  for (int r = 0; r < 4; r++) {
    int row = (wr << 4) + rlo + r;
    int grow = m0 + row;
    if (grow < c) {
      float gwt = sGate[row];
#pragma unroll
      for (int n = 0; n < 2; n++) {
        int col = n0 + (wc << 5) + n * 16 + cl;
        float g = ag[n][r];
        float u = au[n][r];
        float sig = 1.f / (1.f + __expf(-g));
        float h = g * sig * u * gwt;
        hbuf[((size_t)e * CAP + grow) * HEXP + col] = f2bf(h);
      }
    }
  }
}

// ---------------- FFN part 2: 64x128 tile, BK=128, 8 waves, XCD affinity -----------------
// grid 4096; wave (wr 0..3, wc 0..1) owns 16x64 out; small acc -> high occupancy.
__global__ __launch_bounds__(512) void ffn2(const unsigned short* __restrict__ hbuf,
                                            const unsigned short* __restrict__ wdT,
                                            const int* __restrict__ cnt,
                                            const int* __restrict__ listSlot,
                                            float* __restrict__ y) {
  int b = (int)blockIdx.x;
  int xcd = b & 7, slot = b >> 3;
  int e = xcd + 8 * (slot >> 8);        // 256 tiles/expert
  int tile = slot & 255;
  int my = tile >> 3;                   // 0..31 m-tile (64 rows each)
  int nx = tile & 7;                    // 0..7 n-tile (128 wide)
  int c = cnt[e];
  int m0 = my * 64;
  if (m0 >= c) return;
  int n0 = nx * 128;
  __shared__ unsigned short sA[8192];    // 64 x 128
  __shared__ unsigned short sB[16384];   // 128 x 128
  __shared__ int sSlot[64];
  int tid = (int)threadIdx.x;
  if (tid < 64) {
    int r = m0 + tid;
    sSlot[tid] = (r < c) ? listSlot[e * CAP + r] : 0;
  }
  __syncthreads();
  int lane = tid & 63, wid = tid >> 6;
  int wr = wid >> 1, wc = wid & 1;      // wave out: rows wr*16.., cols wc*64..
  const unsigned short* ha = hbuf + ((size_t)e * CAP + m0) * HEXP;
  const unsigned short* wd = wdT + ((size_t)e * DMODEL + n0) * HEXP;
  int rl = lane >> 4;
  int lg = lane & 15;
  const unsigned short* pA[2];
#pragma unroll
  for (int i = 0; i < 2; i++) {
    int lr = wid * 8 + i * 4 + rl;
    int cg = lg ^ (lr & 15);
    pA[i] = ha + (size_t)lr * HEXP + cg * 8;
  }
  const unsigned short* pB[4];
#pragma unroll
  for (int i = 0; i < 4; i++) {
    int lr = wid * 16 + i * 4 + rl;
    int cg = lg ^ (lr & 15);
    pB[i] = wd + (size_t)lr * HEXP + cg * 8;
  }
  f32x4 acc[4];
#pragma unroll
  for (int n = 0; n < 4; n++) acc[n] = f32x4{0, 0, 0, 0};
#pragma unroll 1
  for (int k0 = 0; k0 < HEXP; k0 += 128) {
    __syncthreads();
#pragma unroll
    for (int i = 0; i < 2; i++)
      gl16(pA[i] + k0, sA + (wid * 8 + i * 4) * 128);
#pragma unroll
    for (int i = 0; i < 4; i++)
      gl16(pB[i] + k0, sB + (wid * 16 + i * 4) * 128);
    __syncthreads();
#pragma unroll
    for (int kk = 0; kk < 4; kk++) {
      int kb = (kk << 5) + (rl << 3);
      short8 a, bb[4];
      a = *(const short8*)&sA[SWZ128((wr << 4) + lg, kb)];
#pragma unroll
      for (int n = 0; n < 4; n++)
        bb[n] = *(const short8*)&sB[SWZ128((wc << 6) + lg + n * 16, kb)];
#pragma unroll
      for (int n = 0; n < 4; n++)
        acc[n] = __builtin_amdgcn_mfma_f32_16x16x32_bf16(a, bb[n], acc[n], 0, 0, 0);
    }
  }
  int rlo = (lane >> 4) << 2;
  int cl = lane & 15;
#pragma unroll
  for (int r = 0; r < 4; r++) {
    int row = (wr << 4) + rlo + r;
    int grow = m0 + row;
    if (grow < c) {
      int slot2 = sSlot[row];
#pragma unroll
      for (int n = 0; n < 4; n++) {
        int col = n0 + (wc << 6) + n * 16 + cl;
        y[(size_t)slot2 * DMODEL + col] = acc[n][r];
      }
    }
  }
}

// ---------------- final reduce over the 4 expert slots + scale ---------------------------
__global__ __launch_bounds__(256) void reducek(const float* __restrict__ y,
                                               const float* __restrict__ scale,
                                               float* __restrict__ out) {
  int i = blockIdx.x * 256 + (int)threadIdx.x;
  int t = i >> 8;
  int d = (i & 255) << 2;
  const float* yb = y + (size_t)t * 4 * DMODEL + d;
  f32x4 s = *(const f32x4*)(yb);
  s += *(const f32x4*)(yb + DMODEL);
  s += *(const f32x4*)(yb + 2 * DMODEL);
  s += *(const f32x4*)(yb + 3 * DMODEL);
  float sc = scale[0];
  s *= sc;
  *(f32x4*)(out + (size_t)t * DMODEL + d) = s;
}

extern "C" void kernel_launch(void* const* d_in, const int* in_sizes, int n_in,
                              void* d_out, int out_size, void* d_ws, size_t ws_size,
                              hipStream_t stream) {
  const float* x      = (const float*)d_in[0];
  const float* cen    = (const float*)d_in[1];
  const float* bias   = (const float*)d_in[2];
  const float* w_gate = (const float*)d_in[3];
  const float* w_up   = (const float*)d_in[4];
  const float* w_down = (const float*)d_in[5];
  const float* scale  = (const float*)d_in[6];
  float* out = (float*)d_out;

  char* ws = (char*)d_ws;
  unsigned short* xbf  = (unsigned short*)(ws);                 //  4 MB
  unsigned short* wgT  = (unsigned short*)(ws + 4194304);       // 16 MB  [E][H][D] bf16
  unsigned short* wuT  = (unsigned short*)(ws + 20971520);      // 16 MB
  unsigned short* wdT  = (unsigned short*)(ws + 37748736);      // 16 MB  [E][D][H] bf16
  unsigned short* hbuf = (unsigned short*)(ws + 54525952);      // 32 MB  [E][CAP][H] bf16
  float*          y    = (float*)(ws + 88080384);               // 32 MB  [T*4][D] f32
  int*            cnt  = (int*)(ws + 121634816);
  int*        listTok  = (int*)(ws + 121635072);
  float*     listGate  = (float*)(ws + 121766144);
  int*       listSlot  = (int*)(ws + 121897216);
  int*         selIdx  = (int*)(ws + 122028288);                // 32 KB
  float*      selGate  = (float*)(ws + 122061056);              // 32 KB

  prep<<<dim3(6656), 256, 0, stream>>>(w_gate, w_up, w_down, wgT, wuT, wdT,
                                       x, cen, bias, xbf, selIdx, selGate);
  buildlists<<<dim3(16), 256, 0, stream>>>(selIdx, selGate, cnt, listTok, listGate, listSlot);
  ffn1<<<dim3(4096), 512, 0, stream>>>(xbf, wgT, wuT, cnt, listTok, listGate, hbuf);
  ffn2<<<dim3(4096), 512, 0, stream>>>(hbuf, wdT, cnt, listSlot, y);
  reducek<<<dim3(2048), 256, 0, stream>>>(y, scale, out);
}